// Round 2
// baseline (1358.714 us; speedup 1.0000x reference)
//
#include <hip/hip_runtime.h>
#include <math.h>

#define BB 8
#define CC 256
#define HH 128
#define WW 128
#define NN (HH*WW)          // 16384
#define NBVEC 16
#define CSPLIT 8
#define CCHUNK (CC/CSPLIT)  // 32
#define NBX (NN/256)        // 64

// ---------------- workspace layout (bytes) ----------------
// score  double[B][N]           @ 0        : 1048576
// d2part double[CSPLIT][B][N]   @ 1048576  : 8388608
// wpart  double[NBX][B][C]      @ 9437184  : 1048576
// sumSim double[2][B]           @ 10485760 : 128
// rv     float [B][C]           @ 10485888 : 8192
// bmaxv  double[B][NBX]         @ 10494080 : 4096
// bmaxi  int   [B][NBX]         @ 10498176 : 2048
// total ~10.5 MB

// Control: one block per batch b. Picks the index (N/2 at iter 0, else
// reduces the 64 per-block argmax partials; first-occurrence tie-break),
// bumps selpos, gathers rv[b][:] = x[b][:][sel]. No wsum/repr work here
// (repr finalize is deferred into finish so control never waits on wsum).
__global__ void control_kernel(const float* __restrict__ x, float* __restrict__ out,
                               const double* __restrict__ bmaxv,
                               const int* __restrict__ bmaxi,
                               float* __restrict__ rv, int iter)
{
    const int b = blockIdx.x;
    const int t = threadIdx.x;   // 256 threads

    float* out_selpos = out + (size_t)NBVEC*BB*CC + (size_t)NBVEC*BB*NN;    // [B][N]

    __shared__ double s_val[NBX];
    __shared__ int    s_idx[NBX];
    __shared__ int    s_ind;

    if (iter == 0) {
        if (t == 0) s_ind = NN/2;
    } else {
        if (t < NBX) { s_val[t] = bmaxv[b*NBX + t]; s_idx[t] = bmaxi[b*NBX + t]; }
        __syncthreads();
        for (int s = NBX/2; s > 0; s >>= 1) {
            if (t < s) {
                double v2 = s_val[t+s]; int i2 = s_idx[t+s];
                if (v2 > s_val[t] || (v2 == s_val[t] && i2 < s_idx[t])) {
                    s_val[t] = v2; s_idx[t] = i2;
                }
            }
            __syncthreads();
        }
        if (t == 0) s_ind = s_idx[0];
    }
    __syncthreads();

    const int sel = s_ind;
    if (t == 0) out_selpos[(size_t)b*NN + sel] += 1.0f;
    if (t < CC) rv[(size_t)b*CC + t] = x[(size_t)b*CC*NN + (size_t)t*NN + sel];
}

// Fused kernel: ONE pass over x per iteration (was two + a 256 MB/iter
// simbuf broadcast). Block (nb, cz, b) owns tile c in [cz*32,cz*32+32),
// n in [nb*256, nb*256+256).
//   pass A (iter < NBVEC): stage tile into LDS; d2 partial over 32 c's
//                          per n -> d2part[cz][b][n]  (thread-per-n)
//   pass B (iter > 0):     wsum partial for PREVIOUS iter's sim (fp32
//                          out_sims, 1 KB per block) from the LDS tile
//                          -> wpart[nb][b][c]  (thread-per-(c,g))
// wpart reduction order is fixed (g ascending, k ascending, nb ascending
// in finish) -> deterministic fp64 wsum, no atomics.
__global__ void fused_kernel(const float* __restrict__ x,
                             const float* __restrict__ out,
                             const float* __restrict__ rv,
                             double* __restrict__ d2part,
                             double* __restrict__ wpart, int iter)
{
    const int b  = blockIdx.z;
    const int cz = blockIdx.y;
    const int nb = blockIdx.x;
    const int t  = threadIdx.x;
    const int n  = nb*256 + t;

    __shared__ float  s_x[CCHUNK][257];   // stride 257: pass-B reads 2-way-free
    __shared__ float  s_sim[256];
    __shared__ float  s_rv[CCHUNK];
    __shared__ double s_part[8][CCHUNK];

    if (t < CCHUNK) s_rv[t] = rv[(size_t)b*CC + (size_t)cz*CCHUNK + t];
    if (iter > 0) {
        const float* out_sims = out + (size_t)NBVEC*BB*CC;
        s_sim[t] = out_sims[(size_t)(iter-1)*BB*NN + (size_t)b*NN + n];
    }
    __syncthreads();

    const float* xb = x + (size_t)b*CC*NN + (size_t)cz*CCHUNK*NN;
    double acc = 0.0;
    #pragma unroll 8
    for (int c = 0; c < CCHUNK; ++c) {
        float xv = xb[(size_t)c*NN + n];
        s_x[c][t] = xv;
        if (iter < NBVEC) {
            double diff = (double)xv - (double)s_rv[c];
            acc = fma(diff, diff, acc);
        }
    }
    if (iter < NBVEC) d2part[((size_t)cz*BB + b)*NN + n] = acc;
    __syncthreads();

    if (iter > 0) {
        const int c = t & 31;        // 32 c's
        const int g = t >> 5;        // 8 n-groups of 32
        double w = 0.0;
        #pragma unroll 8
        for (int k = 0; k < 32; ++k) {
            const int nn = g*32 + k;
            w = fma((double)s_sim[nn], (double)s_x[c][nn], w);
        }
        s_part[g][c] = w;
        __syncthreads();
        if (t < CCHUNK) {
            double tot = 0.0;
            #pragma unroll
            for (int gg = 0; gg < 8; ++gg) tot += s_part[gg][t];
            wpart[((size_t)nb*BB + b)*CC + (size_t)cz*CCHUNK + t] = tot;
        }
    }
}

// Finisher: grid (N/256, B).
//  - d2 = sum of 8 fixed-order partials; sim = exp(-sqrt(d2+1e-12)/20)
//  - write out_sims (fp32), score update (fp64), block-reduce sumSim into
//    slot iter&1, block-argmax partials for control
//  - block (0,b), iter>0: finalize repr_{iter-1} = (sum_nb wpart)/sumSim_{iter-1}
//    then zero the consumed sumSim slot.
__global__ void finish_kernel(float* __restrict__ out,
                              double* __restrict__ score,
                              const double* __restrict__ d2part,
                              double* __restrict__ sumSim,
                              const double* __restrict__ wpart,
                              double* __restrict__ bmaxv,
                              int* __restrict__ bmaxi, int iter)
{
    const int b = blockIdx.y;
    const int t = threadIdx.x;
    const int n = blockIdx.x * 256 + t;
    const size_t si = (size_t)b*NN + n;

    double d2 = 0.0;
    #pragma unroll
    for (int cz = 0; cz < CSPLIT; ++cz)
        d2 += d2part[((size_t)cz*BB + b)*NN + n];

    double d   = sqrt(d2 + 1e-12);
    double sim = exp(-(d / 20.0));

    float* out_sims = out + (size_t)NBVEC*BB*CC;   // [NBVEC][B][N]
    out_sims[(size_t)iter*BB*NN + si] = (float)sim;

    double sc;
    if (iter == 0) sc = 1.0 - sim;
    else           sc = (1.0 - sim) * score[si];
    score[si] = sc;

    // block-reduce sumSim (same 256-n grouping as baseline -> identical partials)
    __shared__ double s_red[256];
    s_red[t] = sim;
    __syncthreads();
    for (int s = 128; s > 0; s >>= 1) {
        if (t < s) s_red[t] += s_red[t+s];
        __syncthreads();
    }
    if (t == 0) atomicAdd(&sumSim[(size_t)(iter & 1)*BB + b], s_red[0]);

    // block argmax of updated score (first-occurrence tie-break)
    __shared__ double s_val[256];
    __shared__ int    s_idx[256];
    s_val[t] = sc; s_idx[t] = n;
    __syncthreads();
    for (int s = 128; s > 0; s >>= 1) {
        if (t < s) {
            double v2 = s_val[t+s]; int i2 = s_idx[t+s];
            if (v2 > s_val[t] || (v2 == s_val[t] && i2 < s_idx[t])) {
                s_val[t] = v2; s_idx[t] = i2;
            }
        }
        __syncthreads();
    }
    if (t == 0) {
        bmaxv[(size_t)b*NBX + blockIdx.x] = s_val[0];
        bmaxi[(size_t)b*NBX + blockIdx.x] = s_idx[0];
    }

    // deferred repr finalize for the PREVIOUS iteration (deterministic sum)
    if (iter > 0 && blockIdx.x == 0) {
        const int slotPrev = (iter-1) & 1;
        double ss = sumSim[(size_t)slotPrev*BB + b];
        if (t < CC) {
            double tot = 0.0;
            for (int nb = 0; nb < NBX; ++nb)
                tot += wpart[((size_t)nb*BB + b)*CC + t];
            out[(size_t)(iter-1)*BB*CC + (size_t)b*CC + t] = (float)(tot / ss);
        }
        __syncthreads();
        if (t == 0) sumSim[(size_t)slotPrev*BB + b] = 0.0;
    }
}

// Final repr (iter 15): wpart from the tail fused call, sumSim slot 15&1.
__global__ void final_repr_kernel(float* __restrict__ out,
                                  const double* __restrict__ sumSim,
                                  const double* __restrict__ wpart)
{
    const int b = blockIdx.x;
    const int t = threadIdx.x;
    double ss = sumSim[(size_t)((NBVEC-1) & 1)*BB + b];
    if (t < CC) {
        double tot = 0.0;
        for (int nb = 0; nb < NBX; ++nb)
            tot += wpart[((size_t)nb*BB + b)*CC + t];
        out[(size_t)(NBVEC-1)*BB*CC + (size_t)b*CC + t] = (float)(tot / ss);
    }
}

extern "C" void kernel_launch(void* const* d_in, const int* in_sizes, int n_in,
                              void* d_out, int out_size, void* d_ws, size_t ws_size,
                              hipStream_t stream)
{
    const float* x = (const float*)d_in[0];
    // d_in[1] (prior) is provably unused: ind at i==0 is forced to N/2 and
    // score is overwritten with (1 - sim) at i==0, discarding the prior.
    // d_in[2] (nbVec) fixed at 16 by the problem shapes.
    float* out = (float*)d_out;

    char* ws = (char*)d_ws;
    double* score  = (double*)(ws);
    double* d2part = (double*)(ws + 1048576);
    double* wpart  = (double*)(ws + 9437184);
    double* sumSim = (double*)(ws + 10485760);
    float*  rv     = (float*) (ws + 10485888);
    double* bmaxv  = (double*)(ws + 10494080);
    int*    bmaxi  = (int*)   (ws + 10498176);

    // d_out/d_ws are poisoned before every launch: zero what we accumulate into.
    float* out_selpos = out + (size_t)NBVEC*BB*CC + (size_t)NBVEC*BB*NN;
    hipMemsetAsync(out_selpos, 0, (size_t)BB*NN*sizeof(float), stream);
    hipMemsetAsync(sumSim, 0, 2*BB*sizeof(double), stream);

    for (int i = 0; i <= NBVEC; ++i) {
        if (i < NBVEC)
            control_kernel<<<BB, 256, 0, stream>>>(x, out, bmaxv, bmaxi, rv, i);
        // F(i): d2 for rv_i (skipped at i==16) + wsum for sim_{i-1} (skipped at i==0)
        fused_kernel<<<dim3(NBX, CSPLIT, BB), 256, 0, stream>>>(
            x, out, rv, d2part, wpart, i);
        if (i < NBVEC)
            finish_kernel<<<dim3(NBX, BB), 256, 0, stream>>>(
                out, score, d2part, sumSim, wpart, bmaxv, bmaxi, i);
    }
    final_repr_kernel<<<BB, 256, 0, stream>>>(out, sumSim, wpart);
}

// Round 3
// 839.684 us; speedup vs baseline: 1.6181x; 1.6181x over previous
//
#include <hip/hip_runtime.h>
#include <math.h>

#define BB 8
#define CC 256
#define HH 128
#define WW 128
#define NN (HH*WW)          // 16384
#define NBVEC 16
#define CSPLIT 16
#define CCHUNK (CC/CSPLIT)  // 16
#define NBX (NN/256)        // 64

// ---------------- workspace layout (bytes) ----------------
// score  double[B][N]           @ 0        : 1048576
// d2part double[CSPLIT][B][N]   @ 1048576  : 16777216
// wpart  double[NBX][B][C]      @ 17825792 : 1048576
// sumSim double[2][B]           @ 18874368 : 128
// bmaxv  double[B][NBX]         @ 18874496 : 4096
// bmaxi  int   [B][NBX]         @ 18878592 : 2048
// total ~18.9 MB

// Fused kernel: ONE pass over x per iteration. Block (nb, cz, b) owns
// c in [cz*16, cz*16+16), n in [nb*256, nb*256+256).
//   - every block redundantly reduces the 64 argmax partials -> sel
//     (replaces the control kernel; L2-hot, ~100 cycles)
//   - gathers its own 16 rv values from x at column sel
//   - register-stages 16 x-values per thread (16 loads in flight),
//     writes LDS tile, fp64 d2 partial -> d2part[cz][b][n]
//   - pass B (iter>0): wsum partial for PREVIOUS iter's sim (fp32
//     out_sims) from the LDS tile -> wpart[nb][b][c]
// LDS ~19.6 KB (union overlays argmax scratch with pass-B scratch)
// -> 8 blocks/CU = 32 waves/CU (was 4 blocks / 39% occupancy: the
// round-2 kernel was latency-bound at 1.37 TB/s effective).
__global__ __launch_bounds__(256, 8)
void fused_kernel(const float* __restrict__ x,
                  float* __restrict__ out,
                  const double* __restrict__ bmaxv,
                  const int* __restrict__ bmaxi,
                  double* __restrict__ d2part,
                  double* __restrict__ wpart, int iter)
{
    const int b  = blockIdx.z;
    const int cz = blockIdx.y;
    const int nb = blockIdx.x;
    const int t  = threadIdx.x;
    const int n  = nb*256 + t;

    __shared__ float s_x[CCHUNK][257];   // stride 257: pass-B reads 2-way (free)
    __shared__ float s_sim[256];
    __shared__ float s_rv[CCHUNK];
    __shared__ union UScratch {
        double part[16][CCHUNK];                    // pass-B partials
        struct { double val[NBX]; int idx[NBX]; } mx;  // argmax reduce
    } s_u;

    float* out_sims   = out + (size_t)NBVEC*BB*CC;            // [NBVEC][B][N]
    float* out_selpos = out_sims + (size_t)NBVEC*BB*NN;       // [B][N]

    // ---- select index (redundant per block; first-occurrence tie-break) ----
    int sel = NN/2;
    if (iter > 0 && iter < NBVEC) {
        if (t < NBX) { s_u.mx.val[t] = bmaxv[b*NBX + t]; s_u.mx.idx[t] = bmaxi[b*NBX + t]; }
        __syncthreads();
        for (int s = NBX/2; s > 0; s >>= 1) {
            if (t < s) {
                double v2 = s_u.mx.val[t+s]; int i2 = s_u.mx.idx[t+s];
                if (v2 > s_u.mx.val[t] || (v2 == s_u.mx.val[t] && i2 < s_u.mx.idx[t])) {
                    s_u.mx.val[t] = v2; s_u.mx.idx[t] = i2;
                }
            }
            __syncthreads();
        }
        sel = s_u.mx.idx[0];   // read into register before union is reused
    }

    if (iter < NBVEC) {
        if (t < CCHUNK)
            s_rv[t] = x[((size_t)b*CC + (size_t)cz*CCHUNK + t)*NN + sel];
        if (t == 0 && nb == 0 && cz == 0)
            out_selpos[(size_t)b*NN + sel] += 1.0f;
    }
    if (iter > 0)
        s_sim[t] = out_sims[(size_t)(iter-1)*BB*NN + (size_t)b*NN + n];
    __syncthreads();

    // ---- register-stage the x tile (16 loads back-to-back = full MLP) ----
    const float* xb = x + ((size_t)b*CC + (size_t)cz*CCHUNK)*NN;
    float r[CCHUNK];
    #pragma unroll
    for (int c = 0; c < CCHUNK; ++c)
        r[c] = xb[(size_t)c*NN + n];
    #pragma unroll
    for (int c = 0; c < CCHUNK; ++c)
        s_x[c][t] = r[c];

    // ---- pass A: d2 partial (fp64, fixed c-ascending order) ----
    if (iter < NBVEC) {
        double acc = 0.0;
        #pragma unroll
        for (int c = 0; c < CCHUNK; ++c) {
            double diff = (double)r[c] - (double)s_rv[c];
            acc = fma(diff, diff, acc);
        }
        d2part[((size_t)cz*BB + b)*NN + n] = acc;
    }
    __syncthreads();

    // ---- pass B: wsum partial for previous iter's sim ----
    if (iter > 0) {
        const int c = t & 15;        // 16 c's
        const int g = t >> 4;        // 16 n-groups of 16
        double w = 0.0;
        #pragma unroll
        for (int k = 0; k < 16; ++k) {
            const int nn2 = g*16 + k;
            w = fma((double)s_sim[nn2], (double)s_x[c][nn2], w);
        }
        s_u.part[g][c] = w;
        __syncthreads();
        if (t < CCHUNK) {
            double tot = 0.0;
            #pragma unroll
            for (int gg = 0; gg < 16; ++gg) tot += s_u.part[gg][t];  // fixed order
            wpart[((size_t)nb*BB + b)*CC + (size_t)cz*CCHUNK + t] = tot;
        }
    }
}

// Finisher: grid (N/256, B).
//  - d2 = sum of 16 fixed-order partials; sim = exp(-sqrt(d2+1e-12)/20)
//  - write out_sims (fp32), score update (fp64), block-reduce sumSim into
//    slot iter&1, block-argmax partials for the next fused call
//  - block (0,b), iter>0: finalize repr_{iter-1} = (sum_nb wpart)/sumSim_{iter-1}
//    then zero the consumed sumSim slot.
__global__ void finish_kernel(float* __restrict__ out,
                              double* __restrict__ score,
                              const double* __restrict__ d2part,
                              double* __restrict__ sumSim,
                              const double* __restrict__ wpart,
                              double* __restrict__ bmaxv,
                              int* __restrict__ bmaxi, int iter)
{
    const int b = blockIdx.y;
    const int t = threadIdx.x;
    const int n = blockIdx.x * 256 + t;
    const size_t si = (size_t)b*NN + n;

    double d2 = 0.0;
    #pragma unroll
    for (int cz = 0; cz < CSPLIT; ++cz)
        d2 += d2part[((size_t)cz*BB + b)*NN + n];

    double d   = sqrt(d2 + 1e-12);
    double sim = exp(-(d / 20.0));

    float* out_sims = out + (size_t)NBVEC*BB*CC;   // [NBVEC][B][N]
    out_sims[(size_t)iter*BB*NN + si] = (float)sim;

    double sc;
    if (iter == 0) sc = 1.0 - sim;
    else           sc = (1.0 - sim) * score[si];
    score[si] = sc;

    // block-reduce sumSim (same 256-n grouping as baseline)
    __shared__ double s_red[256];
    s_red[t] = sim;
    __syncthreads();
    for (int s = 128; s > 0; s >>= 1) {
        if (t < s) s_red[t] += s_red[t+s];
        __syncthreads();
    }
    if (t == 0) atomicAdd(&sumSim[(size_t)(iter & 1)*BB + b], s_red[0]);

    // block argmax of updated score (first-occurrence tie-break)
    __shared__ double s_val[256];
    __shared__ int    s_idx[256];
    s_val[t] = sc; s_idx[t] = n;
    __syncthreads();
    for (int s = 128; s > 0; s >>= 1) {
        if (t < s) {
            double v2 = s_val[t+s]; int i2 = s_idx[t+s];
            if (v2 > s_val[t] || (v2 == s_val[t] && i2 < s_idx[t])) {
                s_val[t] = v2; s_idx[t] = i2;
            }
        }
        __syncthreads();
    }
    if (t == 0) {
        bmaxv[(size_t)b*NBX + blockIdx.x] = s_val[0];
        bmaxi[(size_t)b*NBX + blockIdx.x] = s_idx[0];
    }

    // deferred repr finalize for the PREVIOUS iteration (deterministic sum)
    if (iter > 0 && blockIdx.x == 0) {
        const int slotPrev = (iter-1) & 1;
        double ss = sumSim[(size_t)slotPrev*BB + b];
        if (t < CC) {
            double tot = 0.0;
            for (int nb = 0; nb < NBX; ++nb)
                tot += wpart[((size_t)nb*BB + b)*CC + t];
            out[(size_t)(iter-1)*BB*CC + (size_t)b*CC + t] = (float)(tot / ss);
        }
        __syncthreads();
        if (t == 0) sumSim[(size_t)slotPrev*BB + b] = 0.0;
    }
}

// Final repr (iter 15): wpart from the tail fused call, sumSim slot 15&1.
__global__ void final_repr_kernel(float* __restrict__ out,
                                  const double* __restrict__ sumSim,
                                  const double* __restrict__ wpart)
{
    const int b = blockIdx.x;
    const int t = threadIdx.x;
    double ss = sumSim[(size_t)((NBVEC-1) & 1)*BB + b];
    if (t < CC) {
        double tot = 0.0;
        for (int nb = 0; nb < NBX; ++nb)
            tot += wpart[((size_t)nb*BB + b)*CC + t];
        out[(size_t)(NBVEC-1)*BB*CC + (size_t)b*CC + t] = (float)(tot / ss);
    }
}

extern "C" void kernel_launch(void* const* d_in, const int* in_sizes, int n_in,
                              void* d_out, int out_size, void* d_ws, size_t ws_size,
                              hipStream_t stream)
{
    const float* x = (const float*)d_in[0];
    // d_in[1] (prior) is provably unused: ind at i==0 is forced to N/2 and
    // score is overwritten with (1 - sim) at i==0, discarding the prior.
    // d_in[2] (nbVec) fixed at 16 by the problem shapes.
    float* out = (float*)d_out;

    char* ws = (char*)d_ws;
    double* score  = (double*)(ws);
    double* d2part = (double*)(ws + 1048576);
    double* wpart  = (double*)(ws + 17825792);
    double* sumSim = (double*)(ws + 18874368);
    double* bmaxv  = (double*)(ws + 18874496);
    int*    bmaxi  = (int*)   (ws + 18878592);

    // d_out/d_ws are poisoned before every launch: zero what we accumulate into.
    float* out_selpos = out + (size_t)NBVEC*BB*CC + (size_t)NBVEC*BB*NN;
    hipMemsetAsync(out_selpos, 0, (size_t)BB*NN*sizeof(float), stream);
    hipMemsetAsync(sumSim, 0, 2*BB*sizeof(double), stream);

    for (int i = 0; i <= NBVEC; ++i) {
        // F(i): sel+rv from finish(i-1)'s bmax partials, d2 for rv_i
        // (skipped at i==16), wsum for sim_{i-1} (skipped at i==0)
        fused_kernel<<<dim3(NBX, CSPLIT, BB), 256, 0, stream>>>(
            x, out, bmaxv, bmaxi, d2part, wpart, i);
        if (i < NBVEC)
            finish_kernel<<<dim3(NBX, BB), 256, 0, stream>>>(
                out, score, d2part, sumSim, wpart, bmaxv, bmaxi, i);
    }
    final_repr_kernel<<<BB, 256, 0, stream>>>(out, sumSim, wpart);
}